// Round 3
// baseline (842.182 us; speedup 1.0000x reference)
//
#include <hip/hip_runtime.h>

#define KSTATE 64
#define NSAMP  1024

__device__ __forceinline__ float bcast0(float x) {
  return __int_as_float(__builtin_amdgcn_readfirstlane(__float_as_int(x)));
}
__device__ __forceinline__ float rlane(float x, int l) {
  return __int_as_float(__builtin_amdgcn_readlane(__float_as_int(x), l));
}

// One wave (64 threads): row-softmax of T -> expT, log_softmax(pi) -> log_pi, zero out.
__global__ __launch_bounds__(64) void hmm_preproc(
    const float* __restrict__ pi, const float* __restrict__ T,
    float* __restrict__ expT, float* __restrict__ log_pi,
    float* __restrict__ out) {
  const int lane = threadIdx.x;
  float m = -3.4e38f;
  for (int k = 0; k < KSTATE; ++k) m = fmaxf(m, T[lane * KSTATE + k]);
  float s = 0.f;
  for (int k = 0; k < KSTATE; ++k) s += __expf(T[lane * KSTATE + k] - m);
  float inv = 1.0f / s;
  for (int k = 0; k < KSTATE; ++k)
    expT[lane * KSTATE + k] = __expf(T[lane * KSTATE + k] - m) * inv;
  float x = pi[lane];
  float mm = x;
  #pragma unroll
  for (int off = 32; off >= 1; off >>= 1) mm = fmaxf(mm, __shfl_xor(mm, off, 64));
  float e = __expf(x - mm);
  #pragma unroll
  for (int off = 32; off >= 1; off >>= 1) e += __shfl_xor(e, off, 64);
  log_pi[lane] = x - mm - __logf(e);
  if (lane == 0) out[0] = 0.f;  // harness poisons d_out; we atomicAdd into it
}

// Two waves per sequence (block=128 = one pair). Wave h computes the partial
// matvec over j in [32h, 32h+32); halves are combined via a double-buffered
// LDS exchange (+1 barrier/step). Both waves keep the full alpha replicated.
__global__ __launch_bounds__(128) void hmm_forward(
    const float* __restrict__ log_pdf,
    const float* __restrict__ expT,
    const float* __restrict__ log_pi,
    float* __restrict__ out, int N) {
  __shared__ __align__(8) float pbuf[2][2][KSTATE];  // [parity][half][k]
  const int lane = threadIdx.x & 63;
  const int h  = __builtin_amdgcn_readfirstlane(threadIdx.x >> 6);
  const int oh = 1 - h;
  const int jbase = h * 32;
  const int b = blockIdx.x;

  // tcol[jj] = expT[jbase+jj][lane]  (this wave's j-half of the column)
  float tcol[32];
  #pragma unroll
  for (int jj = 0; jj < 32; ++jj) tcol[jj] = expT[(jbase + jj) * KSTATE + lane];

  const float* lp = log_pdf + (size_t)lane * (size_t)N + (size_t)b * NSAMP;

  float4 v0 = *(const float4*)(lp);        // group 0 (t=0..3)
  float4 r1 = *(const float4*)(lp + 4);
  float4 r2 = *(const float4*)(lp + 8);
  float4 r3 = *(const float4*)(lp + 12);

  float x0 = v0.x + log_pi[lane];
  float C = bcast0(x0);
  float a = __expf(x0 - C);

  // One step: partial over this wave's j-half, exchange, combine, scale by E.
#define STEP(E, PAR) do {                                                     \
    float s0 = 0.f, s1 = 0.f, s2 = 0.f, s3 = 0.f;                             \
    _Pragma("unroll")                                                         \
    for (int jj = 0; jj < 32; jj += 4) {                                      \
      float p0 = rlane(a, jbase + jj + 0);                                    \
      float p1 = rlane(a, jbase + jj + 1);                                    \
      float p2 = rlane(a, jbase + jj + 2);                                    \
      float p3 = rlane(a, jbase + jj + 3);                                    \
      s0 = fmaf(p0, tcol[jj + 0], s0);                                        \
      s1 = fmaf(p1, tcol[jj + 1], s1);                                        \
      s2 = fmaf(p2, tcol[jj + 2], s2);                                        \
      s3 = fmaf(p3, tcol[jj + 3], s3);                                        \
    }                                                                         \
    float part = (s0 + s1) + (s2 + s3);                                       \
    pbuf[PAR][h][lane] = part;                                                \
    __syncthreads();                                                          \
    float oth = pbuf[PAR][oh][lane];                                          \
    a = (part + oth) * (E);                                                   \
  } while (0)

  // Renorm every 4 steps (both waves do it identically; exact shift-invariance).
#define RENORM() do {                                                         \
    float c = bcast0(a);                                                      \
    a = a * __builtin_amdgcn_rcpf(c);                                         \
    C += __logf(c);                                                           \
  } while (0)

  {  // steps t = 1..3 from group 0 (parities 0,1,0)
    float e1 = __expf(v0.y), e2 = __expf(v0.z), e3 = __expf(v0.w);
    STEP(e1, 0); STEP(e2, 1); STEP(e3, 0);
    RENORM();
  }

  const int NG = NSAMP / 4;
  for (int g = 1; g < NG; ++g) {
    float4 v = r1; r1 = r2; r2 = r3;
    int gn = (g + 3 < NG) ? (g + 3) : (NG - 1);
    r3 = *(const float4*)(lp + 4 * gn);
    float e0 = __expf(v.x), e1 = __expf(v.y), e2 = __expf(v.z), e3 = __expf(v.w);
    STEP(e0, 1); STEP(e1, 0); STEP(e2, 1); STEP(e3, 0);   // alternation stays globally consistent
    RENORM();
  }
#undef STEP
#undef RENORM

  // out += C + log(sum_k a[k]);  both waves hold identical a, only wave 0 writes.
  float s = a;
  #pragma unroll
  for (int off = 32; off >= 1; off >>= 1) s += __shfl_xor(s, off, 64);
  if (threadIdx.x == 0) atomicAdd(out, C + __logf(s));
}

extern "C" void kernel_launch(void* const* d_in, const int* in_sizes, int n_in,
                              void* d_out, int out_size, void* d_ws, size_t ws_size,
                              hipStream_t stream) {
  const float* log_pdf = (const float*)d_in[0];
  const float* pi      = (const float*)d_in[1];
  const float* T       = (const float*)d_in[2];
  float* out = (float*)d_out;

  float* expT   = (float*)d_ws;              // 64*64 floats
  float* log_pi = expT + KSTATE * KSTATE;    // 64 floats

  const int N = in_sizes[0] / KSTATE;        // 1048576
  const int B = N / NSAMP;                   // 1024 sequences

  hipLaunchKernelGGL(hmm_preproc, dim3(1), dim3(64), 0, stream,
                     pi, T, expT, log_pi, out);
  hipLaunchKernelGGL(hmm_forward, dim3(B), dim3(128), 0, stream,
                     log_pdf, expT, log_pi, out, N);
}

// Round 4
// 513.173 us; speedup vs baseline: 1.6411x; 1.6411x over previous
//
#include <hip/hip_runtime.h>

#define KSTATE 64
#define NSAMP  1024

__device__ __forceinline__ float bcast0(float x) {
  return __int_as_float(__builtin_amdgcn_readfirstlane(__float_as_int(x)));
}
__device__ __forceinline__ float rlane(float x, int l) {
  return __int_as_float(__builtin_amdgcn_readlane(__float_as_int(x), l));
}

// One wave (64 threads): row-softmax of T -> expT, log_softmax(pi) -> log_pi, zero out.
__global__ __launch_bounds__(64) void hmm_preproc(
    const float* __restrict__ pi, const float* __restrict__ T,
    float* __restrict__ expT, float* __restrict__ log_pi,
    float* __restrict__ out) {
  const int lane = threadIdx.x;
  float m = -3.4e38f;
  for (int k = 0; k < KSTATE; ++k) m = fmaxf(m, T[lane * KSTATE + k]);
  float s = 0.f;
  for (int k = 0; k < KSTATE; ++k) s += __expf(T[lane * KSTATE + k] - m);
  float inv = 1.0f / s;
  for (int k = 0; k < KSTATE; ++k)
    expT[lane * KSTATE + k] = __expf(T[lane * KSTATE + k] - m) * inv;
  float x = pi[lane];
  float mm = x;
  #pragma unroll
  for (int off = 32; off >= 1; off >>= 1) mm = fmaxf(mm, __shfl_xor(mm, off, 64));
  float e = __expf(x - mm);
  #pragma unroll
  for (int off = 32; off >= 1; off >>= 1) e += __shfl_xor(e, off, 64);
  log_pi[lane] = x - mm - __logf(e);
  if (lane == 0) out[0] = 0.f;  // harness poisons d_out; we atomicAdd into it
}

// fmac with DPP quad_perm broadcast fused in: all 64 lanes read the quad-lane-Q
// value of SRC. With SRC = a[16*(lane&3)+const], quad-lane Q's value is
// a[16*Q+const] for EVERY quad -> a true wave-wide broadcast, 1 instr per j.
#define FMACQ(ACC, SRC, TC, Q)                                                \
  __asm__ volatile("v_fmac_f32_dpp %0, %1, %2 quad_perm:[" #Q "," #Q "," #Q   \
                   "," #Q "] row_mask:0xf bank_mask:0xf"                      \
                   : "+v"(ACC) : "v"(SRC), "v"(TC))

// 16 fmacs for quad Q (j = 16*Q + 0..15), accumulators c0..c7 two-round cycle.
#define DPPQ(Q) do {                                                          \
    FMACQ(c0, A0.x, tcol[16*Q+ 0], Q); FMACQ(c1, A0.y, tcol[16*Q+ 1], Q);     \
    FMACQ(c2, A0.z, tcol[16*Q+ 2], Q); FMACQ(c3, A0.w, tcol[16*Q+ 3], Q);     \
    FMACQ(c4, A1.x, tcol[16*Q+ 4], Q); FMACQ(c5, A1.y, tcol[16*Q+ 5], Q);     \
    FMACQ(c6, A1.z, tcol[16*Q+ 6], Q); FMACQ(c7, A1.w, tcol[16*Q+ 7], Q);     \
    FMACQ(c0, A2.x, tcol[16*Q+ 8], Q); FMACQ(c1, A2.y, tcol[16*Q+ 9], Q);     \
    FMACQ(c2, A2.z, tcol[16*Q+10], Q); FMACQ(c3, A2.w, tcol[16*Q+11], Q);     \
    FMACQ(c4, A3.x, tcol[16*Q+12], Q); FMACQ(c5, A3.y, tcol[16*Q+13], Q);     \
    FMACQ(c6, A3.z, tcol[16*Q+14], Q); FMACQ(c7, A3.w, tcol[16*Q+15], Q);     \
  } while (0)

// One wave per sequence, scaled-linear-domain forward recurrence.
// Broadcast of a[j]: j<16 via readlane on the live VGPR (covers LDS latency),
// j>=16 via wave-private LDS quad-replication + DPP quad_perm fmacs.
__global__ __launch_bounds__(256) void hmm_forward(
    const float* __restrict__ log_pdf,
    const float* __restrict__ expT,
    const float* __restrict__ log_pi,
    float* __restrict__ out, int N) {
  __shared__ __align__(16) float abuf[4][KSTATE];  // wave-private rows
  const int lane = threadIdx.x & 63;
  const int wave = threadIdx.x >> 6;
  const int b = blockIdx.x * 4 + wave;
  float* ab = abuf[wave];
  const float* myread = ab + 16 * (lane & 3);

  // tcol[j] = expT[j][lane]  (column `lane` of the transition matrix)
  float tcol[KSTATE];
  #pragma unroll
  for (int j = 0; j < KSTATE; ++j) tcol[j] = expT[j * KSTATE + lane];

  const float* lp = log_pdf + (size_t)lane * (size_t)N + (size_t)b * NSAMP;

  float4 v0 = *(const float4*)(lp);        // group 0 (t=0..3)
  float4 r1 = *(const float4*)(lp + 4);
  float4 r2 = *(const float4*)(lp + 8);
  float4 r3 = *(const float4*)(lp + 12);

  float x0 = v0.x + log_pi[lane];
  float C = bcast0(x0);
  float a = __expf(x0 - C);

#define STEP(E) do {                                                          \
    ab[lane] = a;                              /* ds_write_b32 */             \
    float4 A0 = *(const float4*)(myread + 0);  /* a[16(l&3)+ 0.. 3] */        \
    float4 A1 = *(const float4*)(myread + 4);                                 \
    float4 A2 = *(const float4*)(myread + 8);                                 \
    float4 A3 = *(const float4*)(myread + 12);                                \
    /* j = 0..15 via readlane on the live VGPR (independent of LDS) */        \
    float c0 = rlane(a, 0) * tcol[0],  c1 = rlane(a, 1) * tcol[1];            \
    float c2 = rlane(a, 2) * tcol[2],  c3 = rlane(a, 3) * tcol[3];            \
    float c4 = rlane(a, 4) * tcol[4],  c5 = rlane(a, 5) * tcol[5];            \
    float c6 = rlane(a, 6) * tcol[6],  c7 = rlane(a, 7) * tcol[7];            \
    c0 = fmaf(rlane(a,  8), tcol[ 8], c0);                                    \
    c1 = fmaf(rlane(a,  9), tcol[ 9], c1);                                    \
    c2 = fmaf(rlane(a, 10), tcol[10], c2);                                    \
    c3 = fmaf(rlane(a, 11), tcol[11], c3);                                    \
    c4 = fmaf(rlane(a, 12), tcol[12], c4);                                    \
    c5 = fmaf(rlane(a, 13), tcol[13], c5);                                    \
    c6 = fmaf(rlane(a, 14), tcol[14], c6);                                    \
    c7 = fmaf(rlane(a, 15), tcol[15], c7);                                    \
    __asm__ volatile("s_waitcnt lgkmcnt(0)" ::: "memory");                    \
    DPPQ(1); DPPQ(2); DPPQ(3);                 /* j = 16..63, fused bcast */  \
    float sA = (c0 + c1) + (c2 + c3);                                         \
    float sB = (c4 + c5) + (c6 + c7);                                         \
    a = (sA + sB) * (E);                                                      \
  } while (0)

  // Renorm every 4 steps (range analysis: 4-step growth/decay stays well
  // inside fp32; identical math to round 2 which matched exactly).
#define RENORM() do {                                                         \
    float c = bcast0(a);                                                      \
    a = a * __builtin_amdgcn_rcpf(c);                                         \
    C += __logf(c);                                                           \
  } while (0)

  {  // steps t = 1..3 from group 0
    float e1 = __expf(v0.y), e2 = __expf(v0.z), e3 = __expf(v0.w);
    STEP(e1); STEP(e2); STEP(e3);
    RENORM();
  }

  const int NG = NSAMP / 4;
  for (int g = 1; g < NG; ++g) {
    float4 v = r1; r1 = r2; r2 = r3;
    int gn = (g + 3 < NG) ? (g + 3) : (NG - 1);
    r3 = *(const float4*)(lp + 4 * gn);
    float e0 = __expf(v.x), e1 = __expf(v.y), e2 = __expf(v.z), e3 = __expf(v.w);
    STEP(e0); STEP(e1); STEP(e2); STEP(e3);
    RENORM();
  }
#undef STEP
#undef RENORM

  // out += C + log(sum_k a[k])
  float s = a;
  #pragma unroll
  for (int off = 32; off >= 1; off >>= 1) s += __shfl_xor(s, off, 64);
  if (lane == 0) atomicAdd(out, C + __logf(s));
}

extern "C" void kernel_launch(void* const* d_in, const int* in_sizes, int n_in,
                              void* d_out, int out_size, void* d_ws, size_t ws_size,
                              hipStream_t stream) {
  const float* log_pdf = (const float*)d_in[0];
  const float* pi      = (const float*)d_in[1];
  const float* T       = (const float*)d_in[2];
  float* out = (float*)d_out;

  float* expT   = (float*)d_ws;              // 64*64 floats
  float* log_pi = expT + KSTATE * KSTATE;    // 64 floats

  const int N = in_sizes[0] / KSTATE;        // 1048576
  const int B = N / NSAMP;                   // 1024 sequences

  hipLaunchKernelGGL(hmm_preproc, dim3(1), dim3(64), 0, stream,
                     pi, T, expT, log_pi, out);
  hipLaunchKernelGGL(hmm_forward, dim3(B / 4), dim3(256), 0, stream,
                     log_pdf, expT, log_pi, out, N);
}